// Round 3
// baseline (623.199 us; speedup 1.0000x reference)
//
#include <hip/hip_runtime.h>

#define DT 0.1f

__global__ __launch_bounds__(256) void unicycle_kernel(
    const float* __restrict__ v_omega,   // [B][T][2]
    const float* __restrict__ init,      // [B][3]
    float* __restrict__ out,             // [B][T][3]
    int B, int T)
{
    int b = blockIdx.x * blockDim.x + threadIdx.x;
    if (b >= B) return;

    float x  = init[b * 3 + 0];
    float y  = init[b * 3 + 1];
    float th = init[b * 3 + 2];

    const float4* in4  = reinterpret_cast<const float4*>(v_omega + (size_t)b * T * 2);
    float4*       out4 = reinterpret_cast<float4*>(out + (size_t)b * T * 3);

    const int nchunk = T / 4;   // T=200 -> 50 chunks of 4 timesteps

    // prefetch first chunk
    float4 q0 = in4[0];
    float4 q1 = in4[1];

    #pragma unroll 2
    for (int ck = 0; ck < nchunk; ++ck) {
        float4 a  = q0;
        float4 bq = q1;
        // prefetch next chunk while we compute this one (clamped, branch-free)
        int nidx = min(2 * ck + 2, 2 * nchunk - 2);
        q0 = in4[nidx];
        q1 = in4[nidx + 1];

        float o0, o1, o2, o3, o4, o5, o6, o7, o8, o9, o10, o11;
        float s, c;

        th += a.y * DT;  __sincosf(th, &s, &c);  x += a.x * c * DT;  y += a.x * s * DT;
        o0 = x; o1 = y; o2 = th;

        th += a.w * DT;  __sincosf(th, &s, &c);  x += a.z * c * DT;  y += a.z * s * DT;
        o3 = x; o4 = y; o5 = th;

        th += bq.y * DT; __sincosf(th, &s, &c);  x += bq.x * c * DT; y += bq.x * s * DT;
        o6 = x; o7 = y; o8 = th;

        th += bq.w * DT; __sincosf(th, &s, &c);  x += bq.z * c * DT; y += bq.z * s * DT;
        o9 = x; o10 = y; o11 = th;

        out4[3 * ck + 0] = make_float4(o0, o1, o2, o3);
        out4[3 * ck + 1] = make_float4(o4, o5, o6, o7);
        out4[3 * ck + 2] = make_float4(o8, o9, o10, o11);
    }
}

extern "C" void kernel_launch(void* const* d_in, const int* in_sizes, int n_in,
                              void* d_out, int out_size, void* d_ws, size_t ws_size,
                              hipStream_t stream) {
    const float* v_omega = (const float*)d_in[0];
    const float* init    = (const float*)d_in[1];
    float*       out     = (float*)d_out;

    const int B = in_sizes[1] / 3;            // 131072
    const int T = in_sizes[0] / (B * 2);      // 200

    const int block = 256;
    const int grid  = (B + block - 1) / block;
    unicycle_kernel<<<grid, block, 0, stream>>>(v_omega, init, out, B, T);
}